// Round 1
// baseline (243.645 us; speedup 1.0000x reference)
//
#include <hip/hip_runtime.h>
#include <hip/hip_bf16.h>
#include <math.h>

// Problem constants
#define B_ROWS 4096
#define N_ROWS 8192          // 2B
#define D_DIM  1024
#define NCHUNK 16            // m-chunks across grid.y
#define MT_PER_CHUNK 4       // 4 m-tiles of 128 per chunk: 16*4*128 = 8192

#define BM 128
#define BN 128
#define BK 32

typedef __attribute__((ext_vector_type(8))) __bf16 bf16x8;
typedef __attribute__((ext_vector_type(4))) float f32x4;

__device__ __forceinline__ float bf2f(unsigned short u) {
  return __uint_as_float(((unsigned int)u) << 16);
}

__device__ __forceinline__ void load_lds_16B(const void* g, void* l) {
  __builtin_amdgcn_global_load_lds(
      (const __attribute__((address_space(1))) void*)g,
      (__attribute__((address_space(3))) void*)l, 16, 0, 0);
}

// ---------------------------------------------------------------------------
// Kernel 1: row L2-normalize -> bf16 z [8192][1024]; also dn[n] = sum(bf16(z)^2)
// ---------------------------------------------------------------------------
__global__ void normalize_kernel(const float* __restrict__ emb_i,
                                 const float* __restrict__ emb_j,
                                 __hip_bfloat16* __restrict__ z,
                                 float* __restrict__ dn) {
  const int row = blockIdx.x;
  const int tid = threadIdx.x;  // 256 threads, 4 floats each
  const float* src = (row < B_ROWS) ? (emb_i + (size_t)row * D_DIM)
                                    : (emb_j + (size_t)(row - B_ROWS) * D_DIM);
  float4 v = reinterpret_cast<const float4*>(src)[tid];
  float ss = v.x * v.x + v.y * v.y + v.z * v.z + v.w * v.w;
#pragma unroll
  for (int m = 32; m; m >>= 1) ss += __shfl_xor(ss, m, 64);
  __shared__ float red[4];
  const int wave = tid >> 6, lane = tid & 63;
  if (lane == 0) red[wave] = ss;
  __syncthreads();
  const float tot = red[0] + red[1] + red[2] + red[3];
  const float scale = 1.0f / fmaxf(sqrtf(tot), 1e-12f);

  union {
    ushort4 u;
    __hip_bfloat16 h[4];
  } pk;
  pk.h[0] = __float2bfloat16(v.x * scale);
  pk.h[1] = __float2bfloat16(v.y * scale);
  pk.h[2] = __float2bfloat16(v.z * scale);
  pk.h[3] = __float2bfloat16(v.w * scale);
  reinterpret_cast<ushort4*>(z)[(size_t)row * (D_DIM / 4) + tid] = pk.u;

  const float f0 = bf2f(pk.u.x), f1 = bf2f(pk.u.y), f2 = bf2f(pk.u.z),
              f3 = bf2f(pk.u.w);
  float ds = f0 * f0 + f1 * f1 + f2 * f2 + f3 * f3;
#pragma unroll
  for (int m = 32; m; m >>= 1) ds += __shfl_xor(ds, m, 64);
  __syncthreads();
  if (lane == 0) red[wave] = ds;
  __syncthreads();
  if (tid == 0) dn[row] = red[0] + red[1] + red[2] + red[3];
}

// ---------------------------------------------------------------------------
// Kernel 2: pos[n] = dot(z[n], z[n+B]) for n in [0,B)
// ---------------------------------------------------------------------------
__global__ void pos_kernel(const __hip_bfloat16* __restrict__ z,
                           float* __restrict__ pos) {
  const int n = blockIdx.x;     // 0..4095
  const int tid = threadIdx.x;  // 256
  const ushort4* zi =
      reinterpret_cast<const ushort4*>(z + (size_t)n * D_DIM);
  const ushort4* zj =
      reinterpret_cast<const ushort4*>(z + (size_t)(n + B_ROWS) * D_DIM);
  ushort4 a = zi[tid], b = zj[tid];
  float s = bf2f(a.x) * bf2f(b.x) + bf2f(a.y) * bf2f(b.y) +
            bf2f(a.z) * bf2f(b.z) + bf2f(a.w) * bf2f(b.w);
#pragma unroll
  for (int m = 32; m; m >>= 1) s += __shfl_xor(s, m, 64);
  __shared__ float red[4];
  const int wave = tid >> 6, lane = tid & 63;
  if (lane == 0) red[wave] = s;
  __syncthreads();
  if (tid == 0) pos[n] = red[0] + red[1] + red[2] + red[3];
}

// ---------------------------------------------------------------------------
// Kernel 3: fused GEMM + exp + row-sum.
// Block (ntile, chunk): rows [ntile*128, +128), cols [chunk*512, +512).
// partial[n*NCHUNK + chunk] = sum_{m in chunk} exp(2*dot(z_n, z_m))
// ---------------------------------------------------------------------------
__global__ __launch_bounds__(256) void simexp_kernel(
    const __hip_bfloat16* __restrict__ z, float* __restrict__ partial) {
  __shared__ __hip_bfloat16 lds_a[BM * BK];  // 8 KB
  __shared__ __hip_bfloat16 lds_b[BN * BK];  // 8 KB
  __shared__ float rowAcc[BM];

  const int tid = threadIdx.x;
  const int ntile = blockIdx.x;  // 0..63
  const int chunk = blockIdx.y;  // 0..15
  const int row0 = ntile * BM;

  if (tid < BM) rowAcc[tid] = 0.0f;

  const int wave = tid >> 6, lane = tid & 63;
  const int wr = wave >> 1, wc = wave & 1;  // 2x2 wave grid, each 64x64
  const int l15 = lane & 15, l4 = lane >> 4;

  f32x4 acc[4][4];
  const float C2 = 2.8853900817779268f;  // 2*log2(e): exp(2x) = exp2(C2*x)

  for (int mt = 0; mt < MT_PER_CHUNK; ++mt) {
    const int m0 = chunk * (MT_PER_CHUNK * BN) + mt * BN;
#pragma unroll
    for (int mi = 0; mi < 4; ++mi)
#pragma unroll
      for (int ni = 0; ni < 4; ++ni) acc[mi][ni] = (f32x4){0.f, 0.f, 0.f, 0.f};

    for (int kt = 0; kt < D_DIM; kt += BK) {
      __syncthreads();  // previous-iter frag reads done before restage
#pragma unroll
      for (int it = 0; it < 2; ++it) {
        const int t = it * 256 + tid;  // 0..511
        const int r = t >> 2;
        const int kk = (t & 3) * 8;
        load_lds_16B(z + (size_t)(row0 + r) * D_DIM + kt + kk, &lds_a[t * 8]);
      }
#pragma unroll
      for (int it = 0; it < 2; ++it) {
        const int t = it * 256 + tid;
        const int r = t >> 2;
        const int kk = (t & 3) * 8;
        load_lds_16B(z + (size_t)(m0 + r) * D_DIM + kt + kk, &lds_b[t * 8]);
      }
      __syncthreads();  // compiler drains vmcnt before s_barrier

      bf16x8 af[4], bfr[4];
#pragma unroll
      for (int mi = 0; mi < 4; ++mi)
        af[mi] = *reinterpret_cast<const bf16x8*>(
            &lds_a[(wr * 64 + mi * 16 + l15) * BK + l4 * 8]);
#pragma unroll
      for (int ni = 0; ni < 4; ++ni)
        bfr[ni] = *reinterpret_cast<const bf16x8*>(
            &lds_b[(wc * 64 + ni * 16 + l15) * BK + l4 * 8]);
#pragma unroll
      for (int mi = 0; mi < 4; ++mi)
#pragma unroll
        for (int ni = 0; ni < 4; ++ni)
          acc[mi][ni] = __builtin_amdgcn_mfma_f32_16x16x32_bf16(
              af[mi], bfr[ni], acc[mi][ni], 0, 0, 0);
    }

    // epilogue: exp(2*sim) + row-sum over this 128x128 tile
    // C/D layout: value(lane, reg j) = sim[row0 + wr*64 + mi*16 + (lane>>4)*4 + j]
    //                                     [m0 + wc*64 + ni*16 + (lane&15)]
#pragma unroll
    for (int mi = 0; mi < 4; ++mi) {
#pragma unroll
      for (int j = 0; j < 4; ++j) {
        float s = 0.0f;
#pragma unroll
        for (int ni = 0; ni < 4; ++ni) s += exp2f(acc[mi][ni][j] * C2);
        s += __shfl_xor(s, 1, 64);
        s += __shfl_xor(s, 2, 64);
        s += __shfl_xor(s, 4, 64);
        s += __shfl_xor(s, 8, 64);
        if (l15 == 0)
          atomicAdd(&rowAcc[wr * 64 + mi * 16 + l4 * 4 + j], s);
      }
    }
  }
  __syncthreads();
  if (tid < BM)
    partial[(size_t)(row0 + tid) * NCHUNK + chunk] = rowAcc[tid];
}

// ---------------------------------------------------------------------------
// Kernel 4: final reduce -> scalar loss
// ---------------------------------------------------------------------------
__global__ void finalize_kernel(const float* __restrict__ partial,
                                const float* __restrict__ dn,
                                const float* __restrict__ pos,
                                float* __restrict__ out) {
  const int tid = threadIdx.x;  // 256
  const float C2 = 2.8853900817779268f;
  float acc = 0.0f;
  for (int n = tid; n < N_ROWS; n += 256) {
    float S = 0.0f;
#pragma unroll
    for (int c = 0; c < NCHUNK; ++c) S += partial[(size_t)n * NCHUNK + c];
    const float den = S - exp2f(dn[n] * C2);  // remove self-similarity term
    const float p = pos[(n < B_ROWS) ? n : (n - B_ROWS)];
    acc += -2.0f * p + logf(den);
  }
#pragma unroll
  for (int m = 32; m; m >>= 1) acc += __shfl_xor(acc, m, 64);
  __shared__ float red[4];
  const int wave = tid >> 6, lane = tid & 63;
  if (lane == 0) red[wave] = acc;
  __syncthreads();
  if (tid == 0) out[0] = (red[0] + red[1] + red[2] + red[3]) / (float)N_ROWS;
}

// ---------------------------------------------------------------------------
extern "C" void kernel_launch(void* const* d_in, const int* in_sizes, int n_in,
                              void* d_out, int out_size, void* d_ws,
                              size_t ws_size, hipStream_t stream) {
  const float* emb_i = (const float*)d_in[0];
  const float* emb_j = (const float*)d_in[1];
  float* out = (float*)d_out;

  // workspace layout
  __hip_bfloat16* z = (__hip_bfloat16*)d_ws;                      // 16 MB
  char* p = (char*)d_ws + (size_t)N_ROWS * D_DIM * 2;
  float* partial = (float*)p;                                     // 512 KB
  p += (size_t)N_ROWS * NCHUNK * sizeof(float);
  float* dn = (float*)p;                                          // 32 KB
  p += (size_t)N_ROWS * sizeof(float);
  float* pos = (float*)p;                                         // 16 KB

  normalize_kernel<<<N_ROWS, 256, 0, stream>>>(emb_i, emb_j, z, dn);
  pos_kernel<<<B_ROWS, 256, 0, stream>>>(z, pos);
  simexp_kernel<<<dim3(64, NCHUNK), 256, 0, stream>>>(z, partial);
  finalize_kernel<<<1, 256, 0, stream>>>(partial, dn, pos, out);
}

// Round 2
// 177.216 us; speedup vs baseline: 1.3748x; 1.3748x over previous
//
#include <hip/hip_runtime.h>
#include <hip/hip_bf16.h>
#include <math.h>

// Problem constants
#define B_ROWS 4096
#define N_ROWS 8192          // 2B
#define D_DIM  1024
#define NTILES 64            // 8192 / 128
#define NSLOT  64            // partial slots per row = one per "other" tile
#define NPAIRS (NTILES * (NTILES + 1) / 2)  // 2080 upper-triangle tile pairs

#define BM 128
#define BN 128
#define BK 32

typedef __attribute__((ext_vector_type(8))) __bf16 bf16x8;
typedef __attribute__((ext_vector_type(4))) float f32x4;

__device__ __forceinline__ float bf2f(unsigned short u) {
  return __uint_as_float(((unsigned int)u) << 16);
}

__device__ __forceinline__ void load_lds_16B(const void* g, void* l) {
  __builtin_amdgcn_global_load_lds(
      (const __attribute__((address_space(1))) void*)g,
      (__attribute__((address_space(3))) void*)l, 16, 0, 0);
}

// ---------------------------------------------------------------------------
// Kernel 1: row L2-normalize -> bf16 z [8192][1024]; also dn[n] = sum(bf16(z)^2)
// ---------------------------------------------------------------------------
__global__ void normalize_kernel(const float* __restrict__ emb_i,
                                 const float* __restrict__ emb_j,
                                 __hip_bfloat16* __restrict__ z,
                                 float* __restrict__ dn) {
  const int row = blockIdx.x;
  const int tid = threadIdx.x;  // 256 threads, 4 floats each
  const float* src = (row < B_ROWS) ? (emb_i + (size_t)row * D_DIM)
                                    : (emb_j + (size_t)(row - B_ROWS) * D_DIM);
  float4 v = reinterpret_cast<const float4*>(src)[tid];
  float ss = v.x * v.x + v.y * v.y + v.z * v.z + v.w * v.w;
#pragma unroll
  for (int m = 32; m; m >>= 1) ss += __shfl_xor(ss, m, 64);
  __shared__ float red[4];
  const int wave = tid >> 6, lane = tid & 63;
  if (lane == 0) red[wave] = ss;
  __syncthreads();
  const float tot = red[0] + red[1] + red[2] + red[3];
  const float scale = 1.0f / fmaxf(sqrtf(tot), 1e-12f);

  union {
    ushort4 u;
    __hip_bfloat16 h[4];
  } pk;
  pk.h[0] = __float2bfloat16(v.x * scale);
  pk.h[1] = __float2bfloat16(v.y * scale);
  pk.h[2] = __float2bfloat16(v.z * scale);
  pk.h[3] = __float2bfloat16(v.w * scale);
  reinterpret_cast<ushort4*>(z)[(size_t)row * (D_DIM / 4) + tid] = pk.u;

  const float f0 = bf2f(pk.u.x), f1 = bf2f(pk.u.y), f2 = bf2f(pk.u.z),
              f3 = bf2f(pk.u.w);
  float ds = f0 * f0 + f1 * f1 + f2 * f2 + f3 * f3;
#pragma unroll
  for (int m = 32; m; m >>= 1) ds += __shfl_xor(ds, m, 64);
  __syncthreads();
  if (lane == 0) red[wave] = ds;
  __syncthreads();
  if (tid == 0) dn[row] = red[0] + red[1] + red[2] + red[3];
}

// ---------------------------------------------------------------------------
// Kernel 2: pos[n] = dot(z[n], z[n+B]) for n in [0,B)
// ---------------------------------------------------------------------------
__global__ void pos_kernel(const __hip_bfloat16* __restrict__ z,
                           float* __restrict__ pos) {
  const int n = blockIdx.x;     // 0..4095
  const int tid = threadIdx.x;  // 256
  const ushort4* zi =
      reinterpret_cast<const ushort4*>(z + (size_t)n * D_DIM);
  const ushort4* zj =
      reinterpret_cast<const ushort4*>(z + (size_t)(n + B_ROWS) * D_DIM);
  ushort4 a = zi[tid], b = zj[tid];
  float s = bf2f(a.x) * bf2f(b.x) + bf2f(a.y) * bf2f(b.y) +
            bf2f(a.z) * bf2f(b.z) + bf2f(a.w) * bf2f(b.w);
#pragma unroll
  for (int m = 32; m; m >>= 1) s += __shfl_xor(s, m, 64);
  __shared__ float red[4];
  const int wave = tid >> 6, lane = tid & 63;
  if (lane == 0) red[wave] = s;
  __syncthreads();
  if (tid == 0) pos[n] = red[0] + red[1] + red[2] + red[3];
}

// ---------------------------------------------------------------------------
// Kernel 3: fused GEMM + exp + row-sum, SYMMETRIC (upper-triangle tile pairs).
// Block handles tile pair (ti, tj), ti <= tj:
//   rows [ti*128, +128) x cols [tj*128, +128).
//   partial[(ti*128+r)*NSLOT + tj] = sum_c exp(2*sim[r][c])   (row sums)
//   partial[(tj*128+c)*NSLOT + ti] = sum_r exp(2*sim[r][c])   (col sums, ti<tj)
// Diagonal pairs write only row sums (self term removed in finalize via dn).
// ---------------------------------------------------------------------------
__global__ __launch_bounds__(256) void simexp_kernel(
    const __hip_bfloat16* __restrict__ z, float* __restrict__ partial) {
  __shared__ __hip_bfloat16 lds_a[BM * BK];  // 8 KB
  __shared__ __hip_bfloat16 lds_b[BN * BK];  // 8 KB
  __shared__ float rowAcc[BM];
  __shared__ float colAcc[BN];

  const int tid = threadIdx.x;

  // triangular decode: blockIdx.x -> (ti, tj), ti <= tj
  int rem = blockIdx.x;
  int ti = 0;
  while (rem >= NTILES - ti) {
    rem -= NTILES - ti;
    ++ti;
  }
  const int tj = ti + rem;
  const bool diag = (ti == tj);
  const int row0 = ti * BM;
  const int m0 = tj * BN;

  if (tid < BM) rowAcc[tid] = 0.0f;
  if (tid < BN) colAcc[tid] = 0.0f;

  const int wave = tid >> 6, lane = tid & 63;
  const int wr = wave >> 1, wc = wave & 1;  // 2x2 wave grid, each 64x64
  const int l15 = lane & 15, l4 = lane >> 4;

  f32x4 acc[4][4];
  const float C2 = 2.8853900817779268f;  // 2*log2(e): exp(2x) = exp2(C2*x)

#pragma unroll
  for (int mi = 0; mi < 4; ++mi)
#pragma unroll
    for (int ni = 0; ni < 4; ++ni) acc[mi][ni] = (f32x4){0.f, 0.f, 0.f, 0.f};

  for (int kt = 0; kt < D_DIM; kt += BK) {
    __syncthreads();  // previous-iter frag reads done before restage
#pragma unroll
    for (int it = 0; it < 2; ++it) {
      const int t = it * 256 + tid;  // 0..511
      const int r = t >> 2;
      const int kk = (t & 3) * 8;
      load_lds_16B(z + (size_t)(row0 + r) * D_DIM + kt + kk, &lds_a[t * 8]);
    }
#pragma unroll
    for (int it = 0; it < 2; ++it) {
      const int t = it * 256 + tid;
      const int r = t >> 2;
      const int kk = (t & 3) * 8;
      load_lds_16B(z + (size_t)(m0 + r) * D_DIM + kt + kk, &lds_b[t * 8]);
    }
    __syncthreads();  // compiler drains vmcnt before s_barrier

    bf16x8 af[4], bfr[4];
#pragma unroll
    for (int mi = 0; mi < 4; ++mi)
      af[mi] = *reinterpret_cast<const bf16x8*>(
          &lds_a[(wr * 64 + mi * 16 + l15) * BK + l4 * 8]);
#pragma unroll
    for (int ni = 0; ni < 4; ++ni)
      bfr[ni] = *reinterpret_cast<const bf16x8*>(
          &lds_b[(wc * 64 + ni * 16 + l15) * BK + l4 * 8]);
#pragma unroll
    for (int mi = 0; mi < 4; ++mi)
#pragma unroll
      for (int ni = 0; ni < 4; ++ni)
        acc[mi][ni] = __builtin_amdgcn_mfma_f32_16x16x32_bf16(
            af[mi], bfr[ni], acc[mi][ni], 0, 0, 0);
  }

  // epilogue: exponentiate in place, then both row- and col-reductions.
  // C/D layout: acc[mi][ni][j] = sim[row0 + wr*64 + mi*16 + l4*4 + j]
  //                                 [m0  + wc*64 + ni*16 + l15]
#pragma unroll
  for (int mi = 0; mi < 4; ++mi)
#pragma unroll
    for (int ni = 0; ni < 4; ++ni)
#pragma unroll
      for (int j = 0; j < 4; ++j)
        acc[mi][ni][j] = exp2f(acc[mi][ni][j] * C2);

  // row sums: fixed (mi, j, l4) -> sum over ni (in-lane) + l15 group (16 lanes)
#pragma unroll
  for (int mi = 0; mi < 4; ++mi) {
#pragma unroll
    for (int j = 0; j < 4; ++j) {
      float s = acc[mi][0][j] + acc[mi][1][j] + acc[mi][2][j] + acc[mi][3][j];
      s += __shfl_xor(s, 1, 64);
      s += __shfl_xor(s, 2, 64);
      s += __shfl_xor(s, 4, 64);
      s += __shfl_xor(s, 8, 64);
      if (l15 == 0) atomicAdd(&rowAcc[wr * 64 + mi * 16 + l4 * 4 + j], s);
    }
  }

  // col sums (only off-diagonal): fixed (ni, l15) -> sum over mi, j (in-lane)
  // + l4 groups (xor 16, 32)
  if (!diag) {
#pragma unroll
    for (int ni = 0; ni < 4; ++ni) {
      float s = 0.0f;
#pragma unroll
      for (int mi = 0; mi < 4; ++mi)
#pragma unroll
        for (int j = 0; j < 4; ++j) s += acc[mi][ni][j];
      s += __shfl_xor(s, 16, 64);
      s += __shfl_xor(s, 32, 64);
      if (l4 == 0) atomicAdd(&colAcc[wc * 64 + ni * 16 + l15], s);
    }
  }

  __syncthreads();
  if (tid < BM) partial[(size_t)(row0 + tid) * NSLOT + tj] = rowAcc[tid];
  if (!diag && tid < BN)
    partial[(size_t)(m0 + tid) * NSLOT + ti] = colAcc[tid];
}

// ---------------------------------------------------------------------------
// Kernel 4: final reduce -> scalar loss
// ---------------------------------------------------------------------------
__global__ void finalize_kernel(const float* __restrict__ partial,
                                const float* __restrict__ dn,
                                const float* __restrict__ pos,
                                float* __restrict__ out) {
  const int tid = threadIdx.x;  // 256
  const float C2 = 2.8853900817779268f;
  float acc = 0.0f;
  for (int n = tid; n < N_ROWS; n += 256) {
    float S = 0.0f;
#pragma unroll
    for (int c = 0; c < NSLOT; ++c) S += partial[(size_t)n * NSLOT + c];
    const float den = S - exp2f(dn[n] * C2);  // remove self-similarity term
    const float p = pos[(n < B_ROWS) ? n : (n - B_ROWS)];
    acc += -2.0f * p + logf(den);
  }
#pragma unroll
  for (int m = 32; m; m >>= 1) acc += __shfl_xor(acc, m, 64);
  __shared__ float red[4];
  const int wave = tid >> 6, lane = tid & 63;
  if (lane == 0) red[wave] = acc;
  __syncthreads();
  if (tid == 0) out[0] = (red[0] + red[1] + red[2] + red[3]) / (float)N_ROWS;
}

// ---------------------------------------------------------------------------
extern "C" void kernel_launch(void* const* d_in, const int* in_sizes, int n_in,
                              void* d_out, int out_size, void* d_ws,
                              size_t ws_size, hipStream_t stream) {
  const float* emb_i = (const float*)d_in[0];
  const float* emb_j = (const float*)d_in[1];
  float* out = (float*)d_out;

  // workspace layout
  __hip_bfloat16* z = (__hip_bfloat16*)d_ws;                      // 16 MB
  char* p = (char*)d_ws + (size_t)N_ROWS * D_DIM * 2;
  float* partial = (float*)p;                                     // 2 MB
  p += (size_t)N_ROWS * NSLOT * sizeof(float);
  float* dn = (float*)p;                                          // 32 KB
  p += (size_t)N_ROWS * sizeof(float);
  float* pos = (float*)p;                                         // 16 KB

  normalize_kernel<<<N_ROWS, 256, 0, stream>>>(emb_i, emb_j, z, dn);
  pos_kernel<<<B_ROWS, 256, 0, stream>>>(z, pos);
  simexp_kernel<<<NPAIRS, 256, 0, stream>>>(z, partial);
  finalize_kernel<<<1, 256, 0, stream>>>(partial, dn, pos, out);
}

// Round 3
// 157.517 us; speedup vs baseline: 1.5468x; 1.1251x over previous
//
#include <hip/hip_runtime.h>
#include <hip/hip_bf16.h>
#include <math.h>

// Problem constants
#define B_ROWS 4096
#define N_ROWS 8192          // 2B
#define D_DIM  1024
#define NTILES 64            // 8192 / 128
#define NSLOT  64            // partial slots per row = one per "other" tile
#define NPAIRS (NTILES * (NTILES + 1) / 2)  // 2080 upper-triangle tile pairs
#define NXCD 8

#define BM 128
#define BN 128
#define BK 64

typedef __attribute__((ext_vector_type(8))) __bf16 bf16x8;
typedef __attribute__((ext_vector_type(4))) float f32x4;

__device__ __forceinline__ float bf2f(unsigned short u) {
  return __uint_as_float(((unsigned int)u) << 16);
}

__device__ __forceinline__ void load_lds_16B(const void* g, void* l) {
  __builtin_amdgcn_global_load_lds(
      (const __attribute__((address_space(1))) void*)g,
      (__attribute__((address_space(3))) void*)l, 16, 0, 0);
}

// ---------------------------------------------------------------------------
// Kernel 1: row L2-normalize -> bf16 z [8192][1024]; also dn[n] = sum(bf16(z)^2)
// ---------------------------------------------------------------------------
__global__ void normalize_kernel(const float* __restrict__ emb_i,
                                 const float* __restrict__ emb_j,
                                 __hip_bfloat16* __restrict__ z,
                                 float* __restrict__ dn) {
  const int row = blockIdx.x;
  const int tid = threadIdx.x;  // 256 threads, 4 floats each
  const float* src = (row < B_ROWS) ? (emb_i + (size_t)row * D_DIM)
                                    : (emb_j + (size_t)(row - B_ROWS) * D_DIM);
  float4 v = reinterpret_cast<const float4*>(src)[tid];
  float ss = v.x * v.x + v.y * v.y + v.z * v.z + v.w * v.w;
#pragma unroll
  for (int m = 32; m; m >>= 1) ss += __shfl_xor(ss, m, 64);
  __shared__ float red[4];
  const int wave = tid >> 6, lane = tid & 63;
  if (lane == 0) red[wave] = ss;
  __syncthreads();
  const float tot = red[0] + red[1] + red[2] + red[3];
  const float scale = 1.0f / fmaxf(sqrtf(tot), 1e-12f);

  union {
    ushort4 u;
    __hip_bfloat16 h[4];
  } pk;
  pk.h[0] = __float2bfloat16(v.x * scale);
  pk.h[1] = __float2bfloat16(v.y * scale);
  pk.h[2] = __float2bfloat16(v.z * scale);
  pk.h[3] = __float2bfloat16(v.w * scale);
  reinterpret_cast<ushort4*>(z)[(size_t)row * (D_DIM / 4) + tid] = pk.u;

  const float f0 = bf2f(pk.u.x), f1 = bf2f(pk.u.y), f2 = bf2f(pk.u.z),
              f3 = bf2f(pk.u.w);
  float ds = f0 * f0 + f1 * f1 + f2 * f2 + f3 * f3;
#pragma unroll
  for (int m = 32; m; m >>= 1) ds += __shfl_xor(ds, m, 64);
  __syncthreads();
  if (lane == 0) red[wave] = ds;
  __syncthreads();
  if (tid == 0) dn[row] = red[0] + red[1] + red[2] + red[3];
}

// ---------------------------------------------------------------------------
// Kernel 2: pos[n] = dot(z[n], z[n+B]) for n in [0,B)
// ---------------------------------------------------------------------------
__global__ void pos_kernel(const __hip_bfloat16* __restrict__ z,
                           float* __restrict__ pos) {
  const int n = blockIdx.x;     // 0..4095
  const int tid = threadIdx.x;  // 256
  const ushort4* zi =
      reinterpret_cast<const ushort4*>(z + (size_t)n * D_DIM);
  const ushort4* zj =
      reinterpret_cast<const ushort4*>(z + (size_t)(n + B_ROWS) * D_DIM);
  ushort4 a = zi[tid], b = zj[tid];
  float s = bf2f(a.x) * bf2f(b.x) + bf2f(a.y) * bf2f(b.y) +
            bf2f(a.z) * bf2f(b.z) + bf2f(a.w) * bf2f(b.w);
#pragma unroll
  for (int m = 32; m; m >>= 1) s += __shfl_xor(s, m, 64);
  __shared__ float red[4];
  const int wave = tid >> 6, lane = tid & 63;
  if (lane == 0) red[wave] = s;
  __syncthreads();
  if (tid == 0) pos[n] = red[0] + red[1] + red[2] + red[3];
}

// ---------------------------------------------------------------------------
// Kernel 3: fused GEMM + exp + row-sum, SYMMETRIC (upper-triangle tile pairs).
// Block handles tile pair (ti, tj), ti <= tj:
//   rows [ti*128, +128) x cols [tj*128, +128).
//   partial[(ti*128+r)*NSLOT + tj] = sum_c exp(2*sim[r][c])   (row sums)
//   partial[(tj*128+c)*NSLOT + ti] = sum_r exp(2*sim[r][c])   (col sums, ti<tj)
// Diagonal pairs write only row sums (self term removed in finalize via dn).
// BK=64: 16 K-iterations, 32 MFMA per barrier-drain.
// ---------------------------------------------------------------------------
__global__ __launch_bounds__(256) void simexp_kernel(
    const __hip_bfloat16* __restrict__ z, float* __restrict__ partial) {
  __shared__ __hip_bfloat16 lds_a[BM * BK];  // 16 KB
  __shared__ __hip_bfloat16 lds_b[BN * BK];  // 16 KB
  __shared__ float rowAcc[BM];
  __shared__ float colAcc[BN];

  const int tid = threadIdx.x;

  // XCD-chunked bijective swizzle (2080 = 8 * 260): hw-consecutive blocks on
  // one XCD get a contiguous chunk of work ids -> shared A-panels stay in L2.
  const int work = (blockIdx.x % NXCD) * (NPAIRS / NXCD) + blockIdx.x / NXCD;

  // triangular decode: work -> (ti, tj), ti <= tj
  int rem = work;
  int ti = 0;
  while (rem >= NTILES - ti) {
    rem -= NTILES - ti;
    ++ti;
  }
  const int tj = ti + rem;
  const bool diag = (ti == tj);
  const int row0 = ti * BM;
  const int m0 = tj * BN;

  if (tid < BM) rowAcc[tid] = 0.0f;
  if (tid < BN) colAcc[tid] = 0.0f;

  const int wave = tid >> 6, lane = tid & 63;
  const int wr = wave >> 1, wc = wave & 1;  // 2x2 wave grid, each 64x64
  const int l15 = lane & 15, l4 = lane >> 4;

  f32x4 acc[4][4];
  const float C2 = 2.8853900817779268f;  // 2*log2(e): exp(2x) = exp2(C2*x)

#pragma unroll
  for (int mi = 0; mi < 4; ++mi)
#pragma unroll
    for (int ni = 0; ni < 4; ++ni) acc[mi][ni] = (f32x4){0.f, 0.f, 0.f, 0.f};

  for (int kt = 0; kt < D_DIM; kt += BK) {
    __syncthreads();  // previous-iter frag reads done before restage
#pragma unroll
    for (int it = 0; it < 4; ++it) {
      const int t = it * 256 + tid;  // 0..1023
      const int r = t >> 3;          // row 0..127
      const int kk = (t & 7) * 8;    // col 0..56 step 8
      load_lds_16B(z + (size_t)(row0 + r) * D_DIM + kt + kk, &lds_a[t * 8]);
    }
#pragma unroll
    for (int it = 0; it < 4; ++it) {
      const int t = it * 256 + tid;
      const int r = t >> 3;
      const int kk = (t & 7) * 8;
      load_lds_16B(z + (size_t)(m0 + r) * D_DIM + kt + kk, &lds_b[t * 8]);
    }
    __syncthreads();  // compiler drains vmcnt before s_barrier

#pragma unroll
    for (int ks = 0; ks < 2; ++ks) {
      bf16x8 af[4], bfr[4];
#pragma unroll
      for (int mi = 0; mi < 4; ++mi)
        af[mi] = *reinterpret_cast<const bf16x8*>(
            &lds_a[(wr * 64 + mi * 16 + l15) * BK + ks * 32 + l4 * 8]);
#pragma unroll
      for (int ni = 0; ni < 4; ++ni)
        bfr[ni] = *reinterpret_cast<const bf16x8*>(
            &lds_b[(wc * 64 + ni * 16 + l15) * BK + ks * 32 + l4 * 8]);
#pragma unroll
      for (int mi = 0; mi < 4; ++mi)
#pragma unroll
        for (int ni = 0; ni < 4; ++ni)
          acc[mi][ni] = __builtin_amdgcn_mfma_f32_16x16x32_bf16(
              af[mi], bfr[ni], acc[mi][ni], 0, 0, 0);
    }
  }

  // epilogue: exponentiate in place, then both row- and col-reductions.
  // C/D layout: acc[mi][ni][j] = sim[row0 + wr*64 + mi*16 + l4*4 + j]
  //                                 [m0  + wc*64 + ni*16 + l15]
#pragma unroll
  for (int mi = 0; mi < 4; ++mi)
#pragma unroll
    for (int ni = 0; ni < 4; ++ni)
#pragma unroll
      for (int j = 0; j < 4; ++j)
        acc[mi][ni][j] = exp2f(acc[mi][ni][j] * C2);

  // row sums: fixed (mi, j, l4) -> sum over ni (in-lane) + l15 group (16 lanes)
#pragma unroll
  for (int mi = 0; mi < 4; ++mi) {
#pragma unroll
    for (int j = 0; j < 4; ++j) {
      float s = acc[mi][0][j] + acc[mi][1][j] + acc[mi][2][j] + acc[mi][3][j];
      s += __shfl_xor(s, 1, 64);
      s += __shfl_xor(s, 2, 64);
      s += __shfl_xor(s, 4, 64);
      s += __shfl_xor(s, 8, 64);
      if (l15 == 0) atomicAdd(&rowAcc[wr * 64 + mi * 16 + l4 * 4 + j], s);
    }
  }

  // col sums (only off-diagonal): fixed (ni, l15) -> sum over mi, j (in-lane)
  // + l4 groups (xor 16, 32)
  if (!diag) {
#pragma unroll
    for (int ni = 0; ni < 4; ++ni) {
      float s = 0.0f;
#pragma unroll
      for (int mi = 0; mi < 4; ++mi)
#pragma unroll
        for (int j = 0; j < 4; ++j) s += acc[mi][ni][j];
      s += __shfl_xor(s, 16, 64);
      s += __shfl_xor(s, 32, 64);
      if (l4 == 0) atomicAdd(&colAcc[wc * 64 + ni * 16 + l15], s);
    }
  }

  __syncthreads();
  if (tid < BM) partial[(size_t)(row0 + tid) * NSLOT + tj] = rowAcc[tid];
  if (!diag && tid < BN)
    partial[(size_t)(m0 + tid) * NSLOT + ti] = colAcc[tid];
}

// ---------------------------------------------------------------------------
// Kernel 4a: per-row loss, block partial sums (32 blocks x 256 threads)
// ---------------------------------------------------------------------------
__global__ void rowloss_kernel(const float* __restrict__ partial,
                               const float* __restrict__ dn,
                               const float* __restrict__ pos,
                               float* __restrict__ blockSum) {
  const int tid = threadIdx.x;
  const int n = blockIdx.x * 256 + tid;  // 0..8191
  const float C2 = 2.8853900817779268f;
  float S = 0.0f;
#pragma unroll
  for (int c = 0; c < NSLOT; ++c) S += partial[(size_t)n * NSLOT + c];
  const float den = S - exp2f(dn[n] * C2);  // remove self-similarity term
  const float p = pos[(n < B_ROWS) ? n : (n - B_ROWS)];
  float acc = -2.0f * p + logf(den);
#pragma unroll
  for (int m = 32; m; m >>= 1) acc += __shfl_xor(acc, m, 64);
  __shared__ float red[4];
  const int wave = tid >> 6, lane = tid & 63;
  if (lane == 0) red[wave] = acc;
  __syncthreads();
  if (tid == 0) blockSum[blockIdx.x] = red[0] + red[1] + red[2] + red[3];
}

// ---------------------------------------------------------------------------
// Kernel 4b: reduce 32 block sums -> scalar loss
// ---------------------------------------------------------------------------
__global__ void final2_kernel(const float* __restrict__ blockSum,
                              float* __restrict__ out) {
  const int tid = threadIdx.x;  // 64
  float v = (tid < 32) ? blockSum[tid] : 0.0f;
#pragma unroll
  for (int m = 32; m; m >>= 1) v += __shfl_xor(v, m, 64);
  if (tid == 0) out[0] = v / (float)N_ROWS;
}

// ---------------------------------------------------------------------------
extern "C" void kernel_launch(void* const* d_in, const int* in_sizes, int n_in,
                              void* d_out, int out_size, void* d_ws,
                              size_t ws_size, hipStream_t stream) {
  const float* emb_i = (const float*)d_in[0];
  const float* emb_j = (const float*)d_in[1];
  float* out = (float*)d_out;

  // workspace layout
  __hip_bfloat16* z = (__hip_bfloat16*)d_ws;                      // 16 MB
  char* p = (char*)d_ws + (size_t)N_ROWS * D_DIM * 2;
  float* partial = (float*)p;                                     // 2 MB
  p += (size_t)N_ROWS * NSLOT * sizeof(float);
  float* dn = (float*)p;                                          // 32 KB
  p += (size_t)N_ROWS * sizeof(float);
  float* pos = (float*)p;                                         // 16 KB
  p += (size_t)B_ROWS * sizeof(float);
  float* blockSum = (float*)p;                                    // 128 B

  normalize_kernel<<<N_ROWS, 256, 0, stream>>>(emb_i, emb_j, z, dn);
  pos_kernel<<<B_ROWS, 256, 0, stream>>>(z, pos);
  simexp_kernel<<<NPAIRS, 256, 0, stream>>>(z, partial);
  rowloss_kernel<<<N_ROWS / 256, 256, 0, stream>>>(partial, dn, pos, blockSum);
  final2_kernel<<<1, 64, 0, stream>>>(blockSum, out);
}

// Round 4
// 146.913 us; speedup vs baseline: 1.6584x; 1.0722x over previous
//
#include <hip/hip_runtime.h>
#include <hip/hip_bf16.h>
#include <math.h>

// Problem constants
#define B_ROWS 4096
#define N_ROWS 8192          // 2B
#define D_DIM  1024
#define NTILES 64            // 8192 / 128
#define NSLOT  64            // partial slots per row = one per "other" tile
#define NPAIRS (NTILES * (NTILES + 1) / 2)  // 2080 upper-triangle tile pairs
#define NXCD 8

#define BM 128
#define BK 32
#define NT (D_DIM / BK)      // 32 K-tiles
#define SLOT_BYTES 16384     // A (8 KB) + B (8 KB) per ring slot
#define RING 4

typedef __attribute__((ext_vector_type(8))) __bf16 bf16x8;
typedef __attribute__((ext_vector_type(4))) float f32x4;

__device__ __forceinline__ float bf2f(unsigned short u) {
  return __uint_as_float(((unsigned int)u) << 16);
}

__device__ __forceinline__ void load_lds_16B(const void* g, void* l) {
  __builtin_amdgcn_global_load_lds(
      (const __attribute__((address_space(1))) void*)g,
      (__attribute__((address_space(3))) void*)l, 16, 0, 0);
}

#define VMCNT8() asm volatile("s_waitcnt vmcnt(8)" ::: "memory")
#define VMCNT4() asm volatile("s_waitcnt vmcnt(4)" ::: "memory")
#define VMCNT0() asm volatile("s_waitcnt vmcnt(0)" ::: "memory")
#define LGKM0()  asm volatile("s_waitcnt lgkmcnt(0)" ::: "memory")
#define BARRIER() asm volatile("s_barrier" ::: "memory")

// ---------------------------------------------------------------------------
// Kernel 1: row L2-normalize -> bf16 z [8192][1024]; also dn[n] = sum(bf16(z)^2)
// ---------------------------------------------------------------------------
__global__ void normalize_kernel(const float* __restrict__ emb_i,
                                 const float* __restrict__ emb_j,
                                 __hip_bfloat16* __restrict__ z,
                                 float* __restrict__ dn) {
  const int row = blockIdx.x;
  const int tid = threadIdx.x;  // 256 threads, 4 floats each
  const float* src = (row < B_ROWS) ? (emb_i + (size_t)row * D_DIM)
                                    : (emb_j + (size_t)(row - B_ROWS) * D_DIM);
  float4 v = reinterpret_cast<const float4*>(src)[tid];
  float ss = v.x * v.x + v.y * v.y + v.z * v.z + v.w * v.w;
#pragma unroll
  for (int m = 32; m; m >>= 1) ss += __shfl_xor(ss, m, 64);
  __shared__ float red[4];
  const int wave = tid >> 6, lane = tid & 63;
  if (lane == 0) red[wave] = ss;
  __syncthreads();
  const float tot = red[0] + red[1] + red[2] + red[3];
  const float scale = 1.0f / fmaxf(sqrtf(tot), 1e-12f);

  union {
    ushort4 u;
    __hip_bfloat16 h[4];
  } pk;
  pk.h[0] = __float2bfloat16(v.x * scale);
  pk.h[1] = __float2bfloat16(v.y * scale);
  pk.h[2] = __float2bfloat16(v.z * scale);
  pk.h[3] = __float2bfloat16(v.w * scale);
  reinterpret_cast<ushort4*>(z)[(size_t)row * (D_DIM / 4) + tid] = pk.u;

  const float f0 = bf2f(pk.u.x), f1 = bf2f(pk.u.y), f2 = bf2f(pk.u.z),
              f3 = bf2f(pk.u.w);
  float ds = f0 * f0 + f1 * f1 + f2 * f2 + f3 * f3;
#pragma unroll
  for (int m = 32; m; m >>= 1) ds += __shfl_xor(ds, m, 64);
  __syncthreads();
  if (lane == 0) red[wave] = ds;
  __syncthreads();
  if (tid == 0) dn[row] = red[0] + red[1] + red[2] + red[3];
}

// ---------------------------------------------------------------------------
// Kernel 2: pos[n] = dot(z[n], z[n+B]) for n in [0,B)
// ---------------------------------------------------------------------------
__global__ void pos_kernel(const __hip_bfloat16* __restrict__ z,
                           float* __restrict__ pos) {
  const int n = blockIdx.x;     // 0..4095
  const int tid = threadIdx.x;  // 256
  const ushort4* zi =
      reinterpret_cast<const ushort4*>(z + (size_t)n * D_DIM);
  const ushort4* zj =
      reinterpret_cast<const ushort4*>(z + (size_t)(n + B_ROWS) * D_DIM);
  ushort4 a = zi[tid], b = zj[tid];
  float s = bf2f(a.x) * bf2f(b.x) + bf2f(a.y) * bf2f(b.y) +
            bf2f(a.z) * bf2f(b.z) + bf2f(a.w) * bf2f(b.w);
#pragma unroll
  for (int m = 32; m; m >>= 1) s += __shfl_xor(s, m, 64);
  __shared__ float red[4];
  const int wave = tid >> 6, lane = tid & 63;
  if (lane == 0) red[wave] = s;
  __syncthreads();
  if (tid == 0) pos[n] = red[0] + red[1] + red[2] + red[3];
}

// ---------------------------------------------------------------------------
// Kernel 3: fused GEMM + exp + row/col-sum, symmetric tile pairs, with a
// ring-4 counted-vmcnt software pipeline (T3+T4), LDS bank swizzle (T2),
// and setprio around the MFMA cluster (T5).
//
// LDS layout per ring slot (16 KB): A[128][32] bf16 at +0, B[128][32] at +8192.
// Within a matrix, element (r,k) lives at byte
//   r*64 + (((k>>3) ^ ((r>>1)&3)) << 4) + (k&7)*2
// (16B-slot XOR swizzle; spreads the 16-lane fragment read 2-way per bank
//  quad = conflict-free).  global_load_lds writes linearly (thread t ->
// bytes [t*16,t*16+16)), so the *source* global address is pre-swizzled.
// ---------------------------------------------------------------------------
__global__ __launch_bounds__(256, 2) void simexp_kernel(
    const __hip_bfloat16* __restrict__ z, float* __restrict__ partial) {
  __shared__ __align__(16) char ldsbuf[RING * SLOT_BYTES];  // 64 KB
  __shared__ float rowAcc[BM];
  __shared__ float colAcc[BM];

  const int tid = threadIdx.x;

  // XCD-chunked bijective swizzle (2080 = 8 * 260).
  const int work = (blockIdx.x % NXCD) * (NPAIRS / NXCD) + blockIdx.x / NXCD;

  // triangular decode: work -> (ti, tj), ti <= tj
  int rem = work;
  int ti = 0;
  while (rem >= NTILES - ti) {
    rem -= NTILES - ti;
    ++ti;
  }
  const int tj = ti + rem;
  const bool diag = (ti == tj);
  const int row0 = ti * BM;
  const int m0 = tj * BM;

  if (tid < BM) rowAcc[tid] = 0.0f;
  else colAcc[tid - BM] = 0.0f;

  const int wave = tid >> 6, lane = tid & 63;
  const int wr = wave >> 1, wc = wave & 1;  // 2x2 wave grid, each 64x64
  const int l15 = lane & 15, l4 = lane >> 4;

  // ---- staging geometry (fixed per thread) ----
  // chunk c = tid (+256): r = c>>2 in [0,64) (+64), q = c&3,
  // source 16B slot s = q ^ ((r>>1)&3)  [same for both chunks since +64 rows]
  const int rs = tid >> 2;
  const int qs = tid & 3;
  const int ss = qs ^ ((rs >> 1) & 3);
  const __hip_bfloat16* gA0 = z + (size_t)(row0 + rs) * D_DIM + ss * 8;
  const __hip_bfloat16* gA1 = z + (size_t)(row0 + rs + 64) * D_DIM + ss * 8;
  const __hip_bfloat16* gB0 = z + (size_t)(m0 + rs) * D_DIM + ss * 8;
  const __hip_bfloat16* gB1 = z + (size_t)(m0 + rs + 64) * D_DIM + ss * 8;
  const int WA0 = tid * 16;
  const int WA1 = tid * 16 + 4096;

  // ---- fragment read offsets (fixed per thread) ----
  int offA[4], offB[4];
#pragma unroll
  for (int mi = 0; mi < 4; ++mi) {
    const int rA = wr * 64 + mi * 16 + l15;
    offA[mi] = rA * 64 + ((l4 ^ ((rA >> 1) & 3)) << 4);
    const int rB = wc * 64 + mi * 16 + l15;
    offB[mi] = rB * 64 + ((l4 ^ ((rB >> 1) & 3)) << 4);
  }

  f32x4 acc[4][4];
#pragma unroll
  for (int mi = 0; mi < 4; ++mi)
#pragma unroll
    for (int ni = 0; ni < 4; ++ni) acc[mi][ni] = (f32x4){0.f, 0.f, 0.f, 0.f};

#define STAGE(kk)                                                      \
  {                                                                    \
    char* slot_ = ldsbuf + ((kk) & 3) * SLOT_BYTES;                    \
    const size_t koff_ = (size_t)(kk) * BK;                            \
    load_lds_16B(gA0 + koff_, slot_ + WA0);                            \
    load_lds_16B(gA1 + koff_, slot_ + WA1);                            \
    load_lds_16B(gB0 + koff_, slot_ + 8192 + WA0);                     \
    load_lds_16B(gB1 + koff_, slot_ + 8192 + WA1);                     \
  }

#define COMPUTE(kk)                                                    \
  {                                                                    \
    const char* slot_ = ldsbuf + ((kk) & 3) * SLOT_BYTES;              \
    bf16x8 af[4], bf[4];                                               \
    _Pragma("unroll") for (int mi = 0; mi < 4; ++mi)                   \
        af[mi] = *reinterpret_cast<const bf16x8*>(slot_ + offA[mi]);   \
    _Pragma("unroll") for (int ni = 0; ni < 4; ++ni)                   \
        bf[ni] =                                                       \
            *reinterpret_cast<const bf16x8*>(slot_ + 8192 + offB[ni]); \
    __builtin_amdgcn_s_setprio(1);                                     \
    _Pragma("unroll") for (int mi = 0; mi < 4; ++mi)                   \
        _Pragma("unroll") for (int ni = 0; ni < 4; ++ni) acc[mi][ni] = \
            __builtin_amdgcn_mfma_f32_16x16x32_bf16(af[mi], bf[ni],    \
                                                    acc[mi][ni], 0, 0, \
                                                    0);                \
    __builtin_amdgcn_s_setprio(0);                                     \
  }

  // prologue: 3 tiles in flight
  STAGE(0);
  STAGE(1);
  STAGE(2);
  VMCNT8();   // tile 0 landed (12 outstanding -> 8)
  BARRIER();

  // steady state: stage k+3, compute k, wait tile k+1 (leave 8 in flight)
  for (int k = 0; k < NT - 3; ++k) {
    STAGE(k + 3);
    COMPUTE(k);
    VMCNT8();
    BARRIER();
  }
  COMPUTE(NT - 3);
  VMCNT4();
  BARRIER();
  COMPUTE(NT - 2);
  VMCNT0();
  BARRIER();
  COMPUTE(NT - 1);

  // ---- epilogue: exp2 + row/col reductions ----
  const float C2 = 2.8853900817779268f;  // 2*log2(e): exp(2x) = exp2(C2*x)
#pragma unroll
  for (int mi = 0; mi < 4; ++mi)
#pragma unroll
    for (int ni = 0; ni < 4; ++ni)
#pragma unroll
      for (int j = 0; j < 4; ++j)
        acc[mi][ni][j] = exp2f(acc[mi][ni][j] * C2);

  // row sums: fixed (mi, j, l4) -> sum over ni (in-lane) + l15 group
#pragma unroll
  for (int mi = 0; mi < 4; ++mi) {
#pragma unroll
    for (int j = 0; j < 4; ++j) {
      float s = acc[mi][0][j] + acc[mi][1][j] + acc[mi][2][j] + acc[mi][3][j];
      s += __shfl_xor(s, 1, 64);
      s += __shfl_xor(s, 2, 64);
      s += __shfl_xor(s, 4, 64);
      s += __shfl_xor(s, 8, 64);
      if (l15 == 0) atomicAdd(&rowAcc[wr * 64 + mi * 16 + l4 * 4 + j], s);
    }
  }

  // col sums (off-diagonal only): fixed (ni, l15) -> sum over mi, j + l4 group
  if (!diag) {
#pragma unroll
    for (int ni = 0; ni < 4; ++ni) {
      float s = 0.0f;
#pragma unroll
      for (int mi = 0; mi < 4; ++mi)
#pragma unroll
        for (int j = 0; j < 4; ++j) s += acc[mi][ni][j];
      s += __shfl_xor(s, 16, 64);
      s += __shfl_xor(s, 32, 64);
      if (l4 == 0) atomicAdd(&colAcc[wc * 64 + ni * 16 + l15], s);
    }
  }

  LGKM0();   // drain own ds_adds before the barrier
  BARRIER();
  if (tid < BM) partial[(size_t)(row0 + tid) * NSLOT + tj] = rowAcc[tid];
  if (!diag && tid >= BM && tid < 2 * BM)
    partial[(size_t)(m0 + tid - BM) * NSLOT + ti] = colAcc[tid - BM];
#undef STAGE
#undef COMPUTE
}

// ---------------------------------------------------------------------------
// Kernel 4a: per-row loss, block partial sums (32 blocks x 256 threads)
// ---------------------------------------------------------------------------
__global__ void rowloss_kernel(const float* __restrict__ partial,
                               const float* __restrict__ dn,
                               const float* __restrict__ pos,
                               float* __restrict__ blockSum) {
  const int tid = threadIdx.x;
  const int n = blockIdx.x * 256 + tid;  // 0..8191
  const float C2 = 2.8853900817779268f;
  float S = 0.0f;
#pragma unroll
  for (int c = 0; c < NSLOT; ++c) S += partial[(size_t)n * NSLOT + c];
  const float den = S - exp2f(dn[n] * C2);  // remove self-similarity term
  const float p = pos[(n < B_ROWS) ? n : (n - B_ROWS)];
  float acc = -2.0f * p + logf(den);
#pragma unroll
  for (int m = 32; m; m >>= 1) acc += __shfl_xor(acc, m, 64);
  __shared__ float red[4];
  const int wave = tid >> 6, lane = tid & 63;
  if (lane == 0) red[wave] = acc;
  __syncthreads();
  if (tid == 0) blockSum[blockIdx.x] = red[0] + red[1] + red[2] + red[3];
}

// ---------------------------------------------------------------------------
// Kernel 4b: reduce 32 block sums -> scalar loss
// ---------------------------------------------------------------------------
__global__ void final2_kernel(const float* __restrict__ blockSum,
                              float* __restrict__ out) {
  const int tid = threadIdx.x;  // 64
  float v = (tid < 32) ? blockSum[tid] : 0.0f;
#pragma unroll
  for (int m = 32; m; m >>= 1) v += __shfl_xor(v, m, 64);
  if (tid == 0) out[0] = v / (float)N_ROWS;
}

// ---------------------------------------------------------------------------
extern "C" void kernel_launch(void* const* d_in, const int* in_sizes, int n_in,
                              void* d_out, int out_size, void* d_ws,
                              size_t ws_size, hipStream_t stream) {
  const float* emb_i = (const float*)d_in[0];
  const float* emb_j = (const float*)d_in[1];
  float* out = (float*)d_out;

  // workspace layout
  __hip_bfloat16* z = (__hip_bfloat16*)d_ws;                      // 16 MB
  char* p = (char*)d_ws + (size_t)N_ROWS * D_DIM * 2;
  float* partial = (float*)p;                                     // 2 MB
  p += (size_t)N_ROWS * NSLOT * sizeof(float);
  float* dn = (float*)p;                                          // 32 KB
  p += (size_t)N_ROWS * sizeof(float);
  float* pos = (float*)p;                                         // 16 KB
  p += (size_t)B_ROWS * sizeof(float);
  float* blockSum = (float*)p;                                    // 128 B

  normalize_kernel<<<N_ROWS, 256, 0, stream>>>(emb_i, emb_j, z, dn);
  pos_kernel<<<B_ROWS, 256, 0, stream>>>(z, pos);
  simexp_kernel<<<NPAIRS, 256, 0, stream>>>(z, partial);
  rowloss_kernel<<<N_ROWS / 256, 256, 0, stream>>>(partial, dn, pos, blockSum);
  final2_kernel<<<1, 64, 0, stream>>>(blockSum, out);
}

// Round 5
// 124.252 us; speedup vs baseline: 1.9609x; 1.1824x over previous
//
#include <hip/hip_runtime.h>
#include <hip/hip_bf16.h>
#include <math.h>

// Problem constants
#define B_ROWS 4096
#define N_ROWS 8192          // 2B
#define D_DIM  1024
#define NTILES 64            // 8192 / 128
#define NSLOT  64            // partial slots per row = one per "other" tile
#define NPAIRS (NTILES * (NTILES + 1) / 2)  // 2080 upper-triangle tile pairs
#define NXCD 8

#define BM 128
#define BK 32
#define NT (D_DIM / BK)      // 32 K-tiles
#define SLOT_BYTES 16384     // A (8 KB) + B (8 KB) per ring slot
#define RING 2               // double buffer: 32 KB -> 4 blocks/CU

typedef __attribute__((ext_vector_type(8))) __bf16 bf16x8;
typedef __attribute__((ext_vector_type(4))) float f32x4;

__device__ __forceinline__ float bf2f(unsigned short u) {
  return __uint_as_float(((unsigned int)u) << 16);
}

__device__ __forceinline__ void load_lds_16B(const void* g, void* l) {
  __builtin_amdgcn_global_load_lds(
      (const __attribute__((address_space(1))) void*)g,
      (__attribute__((address_space(3))) void*)l, 16, 0, 0);
}

#define VMCNT0() asm volatile("s_waitcnt vmcnt(0)" ::: "memory")
#define LGKM0()  asm volatile("s_waitcnt lgkmcnt(0)" ::: "memory")
#define BARRIER() asm volatile("s_barrier" ::: "memory")

// ---------------------------------------------------------------------------
// Kernel 1: row L2-normalize -> bf16 z [8192][1024]; also dn[n] = sum(bf16(z)^2)
// ---------------------------------------------------------------------------
__global__ void normalize_kernel(const float* __restrict__ emb_i,
                                 const float* __restrict__ emb_j,
                                 __hip_bfloat16* __restrict__ z,
                                 float* __restrict__ dn) {
  const int row = blockIdx.x;
  const int tid = threadIdx.x;  // 256 threads, 4 floats each
  const float* src = (row < B_ROWS) ? (emb_i + (size_t)row * D_DIM)
                                    : (emb_j + (size_t)(row - B_ROWS) * D_DIM);
  float4 v = reinterpret_cast<const float4*>(src)[tid];
  float ss = v.x * v.x + v.y * v.y + v.z * v.z + v.w * v.w;
#pragma unroll
  for (int m = 32; m; m >>= 1) ss += __shfl_xor(ss, m, 64);
  __shared__ float red[4];
  const int wave = tid >> 6, lane = tid & 63;
  if (lane == 0) red[wave] = ss;
  __syncthreads();
  const float tot = red[0] + red[1] + red[2] + red[3];
  const float scale = 1.0f / fmaxf(sqrtf(tot), 1e-12f);

  union {
    ushort4 u;
    __hip_bfloat16 h[4];
  } pk;
  pk.h[0] = __float2bfloat16(v.x * scale);
  pk.h[1] = __float2bfloat16(v.y * scale);
  pk.h[2] = __float2bfloat16(v.z * scale);
  pk.h[3] = __float2bfloat16(v.w * scale);
  reinterpret_cast<ushort4*>(z)[(size_t)row * (D_DIM / 4) + tid] = pk.u;

  const float f0 = bf2f(pk.u.x), f1 = bf2f(pk.u.y), f2 = bf2f(pk.u.z),
              f3 = bf2f(pk.u.w);
  float ds = f0 * f0 + f1 * f1 + f2 * f2 + f3 * f3;
#pragma unroll
  for (int m = 32; m; m >>= 1) ds += __shfl_xor(ds, m, 64);
  __syncthreads();
  if (lane == 0) red[wave] = ds;
  __syncthreads();
  if (tid == 0) dn[row] = red[0] + red[1] + red[2] + red[3];
}

// ---------------------------------------------------------------------------
// Kernel 2: pos[n] = dot(z[n], z[n+B]) for n in [0,B)
// ---------------------------------------------------------------------------
__global__ void pos_kernel(const __hip_bfloat16* __restrict__ z,
                           float* __restrict__ pos) {
  const int n = blockIdx.x;     // 0..4095
  const int tid = threadIdx.x;  // 256
  const ushort4* zi =
      reinterpret_cast<const ushort4*>(z + (size_t)n * D_DIM);
  const ushort4* zj =
      reinterpret_cast<const ushort4*>(z + (size_t)(n + B_ROWS) * D_DIM);
  ushort4 a = zi[tid], b = zj[tid];
  float s = bf2f(a.x) * bf2f(b.x) + bf2f(a.y) * bf2f(b.y) +
            bf2f(a.z) * bf2f(b.z) + bf2f(a.w) * bf2f(b.w);
#pragma unroll
  for (int m = 32; m; m >>= 1) s += __shfl_xor(s, m, 64);
  __shared__ float red[4];
  const int wave = tid >> 6, lane = tid & 63;
  if (lane == 0) red[wave] = s;
  __syncthreads();
  if (tid == 0) pos[n] = red[0] + red[1] + red[2] + red[3];
}

// ---------------------------------------------------------------------------
// Kernel 3: fused GEMM + exp + row/col-sum, symmetric tile pairs.
// Ring-2 double buffer (T3 minimum 2-phase): STAGE(k+1) issued BEFORE
// compute(k); single vmcnt(0)+barrier per K-tile. 33.8 KB LDS -> 4 blocks/CU.
// T2 16B-slot XOR swizzle keeps ds_read_b128 conflict-free (verified 0 in R3).
//
// LDS layout per ring slot (16 KB): A[128][32] bf16 at +0, B[128][32] at +8192.
// Element (r,k) at byte r*64 + (((k>>3) ^ ((r>>1)&3)) << 4) + (k&7)*2.
// global_load_lds writes linearly, so the source global address is
// pre-swizzled (both-sides-or-neither rule).
// ---------------------------------------------------------------------------
__global__ __launch_bounds__(256, 4) void simexp_kernel(
    const __hip_bfloat16* __restrict__ z, float* __restrict__ partial) {
  __shared__ __align__(16) char ldsbuf[RING * SLOT_BYTES];  // 32 KB
  __shared__ float rowAcc[BM];
  __shared__ float colAcc[BM];

  const int tid = threadIdx.x;

  // XCD-chunked bijective swizzle (2080 = 8 * 260).
  const int work = (blockIdx.x % NXCD) * (NPAIRS / NXCD) + blockIdx.x / NXCD;

  // triangular decode: work -> (ti, tj), ti <= tj
  int rem = work;
  int ti = 0;
  while (rem >= NTILES - ti) {
    rem -= NTILES - ti;
    ++ti;
  }
  const int tj = ti + rem;
  const bool diag = (ti == tj);
  const int row0 = ti * BM;
  const int m0 = tj * BM;

  if (tid < BM) rowAcc[tid] = 0.0f;
  else colAcc[tid - BM] = 0.0f;

  const int wave = tid >> 6, lane = tid & 63;
  const int wr = wave >> 1, wc = wave & 1;  // 2x2 wave grid, each 64x64
  const int l15 = lane & 15, l4 = lane >> 4;

  // ---- staging geometry (fixed per thread) ----
  const int rs = tid >> 2;
  const int qs = tid & 3;
  const int ss = qs ^ ((rs >> 1) & 3);
  const __hip_bfloat16* gA0 = z + (size_t)(row0 + rs) * D_DIM + ss * 8;
  const __hip_bfloat16* gA1 = z + (size_t)(row0 + rs + 64) * D_DIM + ss * 8;
  const __hip_bfloat16* gB0 = z + (size_t)(m0 + rs) * D_DIM + ss * 8;
  const __hip_bfloat16* gB1 = z + (size_t)(m0 + rs + 64) * D_DIM + ss * 8;
  const int WA0 = tid * 16;
  const int WA1 = tid * 16 + 4096;

  // ---- fragment read offsets (fixed per thread) ----
  int offA[4], offB[4];
#pragma unroll
  for (int mi = 0; mi < 4; ++mi) {
    const int rA = wr * 64 + mi * 16 + l15;
    offA[mi] = rA * 64 + ((l4 ^ ((rA >> 1) & 3)) << 4);
    const int rB = wc * 64 + mi * 16 + l15;
    offB[mi] = rB * 64 + ((l4 ^ ((rB >> 1) & 3)) << 4);
  }

  f32x4 acc[4][4];
#pragma unroll
  for (int mi = 0; mi < 4; ++mi)
#pragma unroll
    for (int ni = 0; ni < 4; ++ni) acc[mi][ni] = (f32x4){0.f, 0.f, 0.f, 0.f};

#define STAGE(kk)                                                      \
  {                                                                    \
    char* slot_ = ldsbuf + ((kk) & (RING - 1)) * SLOT_BYTES;           \
    const size_t koff_ = (size_t)(kk) * BK;                            \
    load_lds_16B(gA0 + koff_, slot_ + WA0);                            \
    load_lds_16B(gA1 + koff_, slot_ + WA1);                            \
    load_lds_16B(gB0 + koff_, slot_ + 8192 + WA0);                     \
    load_lds_16B(gB1 + koff_, slot_ + 8192 + WA1);                     \
  }

#define COMPUTE(kk)                                                    \
  {                                                                    \
    const char* slot_ = ldsbuf + ((kk) & (RING - 1)) * SLOT_BYTES;     \
    bf16x8 af[4], bf[4];                                               \
    _Pragma("unroll") for (int mi = 0; mi < 4; ++mi)                   \
        af[mi] = *reinterpret_cast<const bf16x8*>(slot_ + offA[mi]);   \
    _Pragma("unroll") for (int ni = 0; ni < 4; ++ni)                   \
        bf[ni] =                                                       \
            *reinterpret_cast<const bf16x8*>(slot_ + 8192 + offB[ni]); \
    __builtin_amdgcn_s_setprio(1);                                     \
    _Pragma("unroll") for (int mi = 0; mi < 4; ++mi)                   \
        _Pragma("unroll") for (int ni = 0; ni < 4; ++ni) acc[mi][ni] = \
            __builtin_amdgcn_mfma_f32_16x16x32_bf16(af[mi], bf[ni],    \
                                                    acc[mi][ni], 0, 0, \
                                                    0);                \
    __builtin_amdgcn_s_setprio(0);                                     \
  }

  // prologue
  STAGE(0);
  VMCNT0();
  BARRIER();

  // steady state: issue next tile's loads, compute current, wait, barrier
  for (int k = 0; k < NT - 1; ++k) {
    STAGE(k + 1);
    COMPUTE(k);
    VMCNT0();  // STAGE(k+1) was issued a full compute-phase ago
    BARRIER();
  }
  COMPUTE(NT - 1);

  // ---- epilogue: exp2 + row/col reductions ----
  const float C2 = 2.8853900817779268f;  // 2*log2(e): exp(2x) = exp2(C2*x)
#pragma unroll
  for (int mi = 0; mi < 4; ++mi)
#pragma unroll
    for (int ni = 0; ni < 4; ++ni)
#pragma unroll
      for (int j = 0; j < 4; ++j)
        acc[mi][ni][j] = exp2f(acc[mi][ni][j] * C2);

  // row sums: fixed (mi, j, l4) -> sum over ni (in-lane) + l15 group
#pragma unroll
  for (int mi = 0; mi < 4; ++mi) {
#pragma unroll
    for (int j = 0; j < 4; ++j) {
      float s = acc[mi][0][j] + acc[mi][1][j] + acc[mi][2][j] + acc[mi][3][j];
      s += __shfl_xor(s, 1, 64);
      s += __shfl_xor(s, 2, 64);
      s += __shfl_xor(s, 4, 64);
      s += __shfl_xor(s, 8, 64);
      if (l15 == 0) atomicAdd(&rowAcc[wr * 64 + mi * 16 + l4 * 4 + j], s);
    }
  }

  // col sums (off-diagonal only): fixed (ni, l15) -> sum over mi, j + l4 group
  if (!diag) {
#pragma unroll
    for (int ni = 0; ni < 4; ++ni) {
      float s = 0.0f;
#pragma unroll
      for (int mi = 0; mi < 4; ++mi)
#pragma unroll
        for (int j = 0; j < 4; ++j) s += acc[mi][ni][j];
      s += __shfl_xor(s, 16, 64);
      s += __shfl_xor(s, 32, 64);
      if (l4 == 0) atomicAdd(&colAcc[wc * 64 + ni * 16 + l15], s);
    }
  }

  LGKM0();   // drain own ds_atomics before the barrier
  BARRIER();
  if (tid < BM) partial[(size_t)(row0 + tid) * NSLOT + tj] = rowAcc[tid];
  if (!diag && tid >= BM && tid < 2 * BM)
    partial[(size_t)(m0 + tid - BM) * NSLOT + ti] = colAcc[tid - BM];
#undef STAGE
#undef COMPUTE
}

// ---------------------------------------------------------------------------
// Kernel 4a: per-row loss, block partial sums (32 blocks x 256 threads)
// ---------------------------------------------------------------------------
__global__ void rowloss_kernel(const float* __restrict__ partial,
                               const float* __restrict__ dn,
                               const float* __restrict__ pos,
                               float* __restrict__ blockSum) {
  const int tid = threadIdx.x;
  const int n = blockIdx.x * 256 + tid;  // 0..8191
  const float C2 = 2.8853900817779268f;
  float S = 0.0f;
#pragma unroll
  for (int c = 0; c < NSLOT; ++c) S += partial[(size_t)n * NSLOT + c];
  const float den = S - exp2f(dn[n] * C2);  // remove self-similarity term
  const float p = pos[(n < B_ROWS) ? n : (n - B_ROWS)];
  float acc = -2.0f * p + logf(den);
#pragma unroll
  for (int m = 32; m; m >>= 1) acc += __shfl_xor(acc, m, 64);
  __shared__ float red[4];
  const int wave = tid >> 6, lane = tid & 63;
  if (lane == 0) red[wave] = acc;
  __syncthreads();
  if (tid == 0) blockSum[blockIdx.x] = red[0] + red[1] + red[2] + red[3];
}

// ---------------------------------------------------------------------------
// Kernel 4b: reduce 32 block sums -> scalar loss
// ---------------------------------------------------------------------------
__global__ void final2_kernel(const float* __restrict__ blockSum,
                              float* __restrict__ out) {
  const int tid = threadIdx.x;  // 64
  float v = (tid < 32) ? blockSum[tid] : 0.0f;
#pragma unroll
  for (int m = 32; m; m >>= 1) v += __shfl_xor(v, m, 64);
  if (tid == 0) out[0] = v / (float)N_ROWS;
}

// ---------------------------------------------------------------------------
extern "C" void kernel_launch(void* const* d_in, const int* in_sizes, int n_in,
                              void* d_out, int out_size, void* d_ws,
                              size_t ws_size, hipStream_t stream) {
  const float* emb_i = (const float*)d_in[0];
  const float* emb_j = (const float*)d_in[1];
  float* out = (float*)d_out;

  // workspace layout
  __hip_bfloat16* z = (__hip_bfloat16*)d_ws;                      // 16 MB
  char* p = (char*)d_ws + (size_t)N_ROWS * D_DIM * 2;
  float* partial = (float*)p;                                     // 2 MB
  p += (size_t)N_ROWS * NSLOT * sizeof(float);
  float* dn = (float*)p;                                          // 32 KB
  p += (size_t)N_ROWS * sizeof(float);
  float* pos = (float*)p;                                         // 16 KB
  p += (size_t)B_ROWS * sizeof(float);
  float* blockSum = (float*)p;                                    // 128 B

  normalize_kernel<<<N_ROWS, 256, 0, stream>>>(emb_i, emb_j, z, dn);
  pos_kernel<<<B_ROWS, 256, 0, stream>>>(z, pos);
  simexp_kernel<<<NPAIRS, 256, 0, stream>>>(z, partial);
  rowloss_kernel<<<N_ROWS / 256, 256, 0, stream>>>(partial, dn, pos, blockSum);
  final2_kernel<<<1, 64, 0, stream>>>(blockSum, out);
}